// Round 8
// baseline (18410.918 us; speedup 1.0000x reference)
//
#include <hip/hip_runtime.h>
#include <hip/hip_fp16.h>
#include <cstdint>
#include <cstddef>

#define B_ 256
#define L_ 200
#define S_ 199
#define D_ 256
#define Q_ 20000
#define C_ 500
#define ROWS 2
#define NBLK 128   // NBLK * ROWS == B_

// ---- workspace layout (bytes, 256-aligned) ----
#define OFF_TEPF 0u            // 204800  f32 [200][256]
#define OFF_TESF 204800u       // 204800
#define OFF_CAF  409600u       // 1024
#define OFF_PPF  410624u       // 131072  f16 uint4 [32][256]
#define OFF_PSF  541696u       // 131072
#define OFF_PAF  672768u       // 131072
#define OFF_PAS  803840u       // 262144  [64][256]
#define OFF_PPS  1065984u      // 262144
#define OFF_PSS  1328128u      // 262144
#define OFF_PO1  1590272u      // 524288  [128][256]
#define OFF_LPI  2114560u      // 203776  int [B][S]
#define OFF_LCI  2318336u      // 203776
#define OFF_PSH  2522112u      // 26083328 f16 [B][S][256]
#define OFF_SSH  28605440u     // 26083328
// total 54,688,768 bytes (~52.2 MB)

// TEpf[tau][d] = bpf[d] + sum_k time_embed[tau][k]*Wpf[d][256+k]; same for sf.
__global__ void te_kernel(const float* __restrict__ te,
                          const float* __restrict__ Wpf, const float* __restrict__ bpf,
                          const float* __restrict__ Wsf, const float* __restrict__ bsf,
                          float* __restrict__ TEpf, float* __restrict__ TEsf) {
  int idx = blockIdx.x * 256 + threadIdx.x;
  int tau = idx >> 8, d = idx & 255;
  const float* ter = te + (tau << 8);
  const float* wp = Wpf + d * 512 + 256;
  const float* ws = Wsf + d * 512 + 256;
  float ap = 0.f, as = 0.f;
  for (int k = 0; k < 256; ++k) {
    float x = ter[k];
    ap = fmaf(x, wp[k], ap);
    as = fmaf(x, ws[k], as);
  }
  TEpf[idx] = ap + bpf[d];
  TEsf[idx] = as + bsf[d];
}

__global__ void caf_kernel(const float* __restrict__ te, const float* __restrict__ Waf,
                           const float* __restrict__ baf, float* __restrict__ CAF) {
  int d = threadIdx.x;
  const float* ter = te + 256;
  const float* wa = Waf + d * 512 + 256;
  float a = 0.f;
  for (int k = 0; k < 256; ++k) a = fmaf(ter[k], wa[k], a);
  CAF[d] = a + baf[d];
}

// lpi[b][t] = largest t'<t with nq[b][t']==nq[b][t], else 0 (matches reference
// lpt-table semantics incl. "never seen" -> 0, since step 0 writes history row 0).
__global__ void lastidx_kernel(const int* __restrict__ q_seq, const int* __restrict__ c_seq,
                               int* __restrict__ lpi, int* __restrict__ lci) {
  int b = blockIdx.x;
  int tid = threadIdx.x;
  __shared__ int sq[S_], sc[S_];
  if (tid < S_) {
    sq[tid] = q_seq[b * L_ + tid + 1];
    sc[tid] = c_seq[b * L_ + tid + 1];
  }
  __syncthreads();
  if (tid < S_) {
    int ip = sq[tid], ic = sc[tid];
    int lp = 0, lc = 0;
    for (int u = tid - 1; u >= 0; --u) if (sq[u] == ip) { lp = u; break; }
    for (int u = tid - 1; u >= 0; --u) if (sc[u] == ic) { lc = u; break; }
    lpi[b * S_ + tid] = lp;
    lci[b * S_ + tid] = lc;
  }
}

__device__ __forceinline__ unsigned pk2(float a, float b) {
  __half2 h = __floats2half2_rn(a, b);
  return *(unsigned*)&h;
}

// Pack W[d][8k8..8k8+7] (fp32, row-major (256,fi)) -> out[k8*256+d] as 8x f16 in uint4.
__global__ void pack_kernel(const float* __restrict__ W, uint4* __restrict__ out, int fi) {
  int k8 = blockIdx.x, d = threadIdx.x;
  const float* r = W + d * fi + (k8 << 3);
  out[k8 * 256 + d] = make_uint4(pk2(r[0], r[1]), pk2(r[2], r[3]),
                                 pk2(r[4], r[5]), pk2(r[6], r[7]));
}

typedef _Float16 h2v __attribute__((ext_vector_type(2)));
union U2H { unsigned u; h2v h; __half2 hh; };

__device__ __forceinline__ float fd2(unsigned w, unsigned x, float acc) {
#if __has_builtin(__builtin_amdgcn_fdot2)
  U2H a; a.u = w; U2H b; b.u = x;
  return __builtin_amdgcn_fdot2(a.h, b.h, acc, false);
#else
  U2H a; a.u = w; U2H b; b.u = x;
  acc = fmaf(__low2float(a.hh),  __low2float(b.hh),  acc);
  acc = fmaf(__high2float(a.hh), __high2float(b.hh), acc);
  return acc;
#endif
}
__device__ __forceinline__ float dot8(uint4 w, uint4 x, float acc) {
  acc = fd2(w.x, x.x, acc); acc = fd2(w.y, x.y, acc);
  acc = fd2(w.z, x.z, acc); acc = fd2(w.w, x.w, acc);
  return acc;
}
__device__ __forceinline__ float sigf(float z) { return 1.f / (1.f + __expf(-z)); }
__device__ __forceinline__ float tanh_fast(float z) { return 1.f - 2.f / (__expf(2.f * z) + 1.f); }

// 128 blocks x 1024 threads (16 waves = 4/SIMD). Block owns ROWS=2 rows.
// thread = (d = tid&255, quarter h = tid>>8); 4-way split-K; weight uint4
// loaded once, used for both rows. Partials reduced via LDS; quarter 0
// finalizes. Per-CU weight stream 1.66 MB/step -> ~11.5us/step L2-BW floor.
__global__ __launch_bounds__(1024, 4)
void scan2_kernel(const int* __restrict__ qs, const int* __restrict__ cs,
                  const int* __restrict__ aseq,
                  const float* __restrict__ pro, const float* __restrict__ skill,
                  const float* __restrict__ ansv, const float* __restrict__ lsst,
                  const float* __restrict__ ps0, const float* __restrict__ ss0,
                  const float* __restrict__ adiff, const float* __restrict__ achg,
                  const float* __restrict__ TEpf, const float* __restrict__ TEsf,
                  const float* __restrict__ CAF,
                  const uint4* __restrict__ Ppf, const uint4* __restrict__ Psf,
                  const uint4* __restrict__ Paf,
                  const uint4* __restrict__ Pas, const uint4* __restrict__ Pps,
                  const uint4* __restrict__ Pss, const uint4* __restrict__ Po1,
                  const float* __restrict__ bo1, const float* __restrict__ bas,
                  const float* __restrict__ bps, const float* __restrict__ bss,
                  const float* __restrict__ Wo2, const float* __restrict__ bo2,
                  const int* __restrict__ lpi, const int* __restrict__ lci,
                  __half* __restrict__ psh, __half* __restrict__ ssh,
                  float* __restrict__ out) {
  const int tid = threadIdx.x;
  const int d = tid & 255;
  const int h = tid >> 8;          // quarter 0..3 (wave-uniform)
  const int b0 = blockIdx.x * ROWS;

  __shared__ __align__(16) __half sLP[ROWS][264], sLC[ROWS][264], sAS[ROWS][264];
  __shared__ __align__(16) __half sLA[ROWS][264], sLP2[ROWS][264], sLC2[ROWS][264];
  __shared__ __align__(16) __half sPE[ROWS][264], sX[ROWS][264];
  __shared__ float sTP[ROWS][256], sTC[ROWS][256];
  __shared__ float s_gf[6][256];         // f32 la2/lp2/lc2 (g*2+r)
  __shared__ float s_astf[ROWS][256];
  __shared__ float s_part[8][1024];      // split-K partials
  __shared__ float s_red[4][ROWS];
  __shared__ int s_idx[ROWS][5];         // ip, ic, ia, lpt, lct

  const float caf_d = CAF[d];
  const float bo1_d = bo1[d], bas_d = bas[d], bps_d = bps[d], bss_d = bss[d];
  const float wo2_d = Wo2[d];
  const float bo2v = bo2[0];

  if (tid < 256) {
    float a = lsst[d];
#pragma unroll
    for (int r = 0; r < ROWS; ++r) {
      int row = b0 + r;
      s_astf[r][d] = a;
      sAS[r][d] = __float2half(a);
      // lazy history init: only row 0 is ever read before being written
      psh[(size_t)row * S_ * 256 + d] = __float2half(ps0[d]);
      ssh[(size_t)row * S_ * 256 + d] = __float2half(ss0[d]);
    }
  }
  __syncthreads();

#pragma clang loop unroll(disable)
  for (int t = 0; t < S_; ++t) {
    if (tid < ROWS) {
      int row = b0 + tid;
      s_idx[tid][0] = qs[row * L_ + t + 1];
      s_idx[tid][1] = cs[row * L_ + t + 1];
      s_idx[tid][2] = aseq[row * L_ + t + 1];
      s_idx[tid][3] = lpi[row * S_ + t];
      s_idx[tid][4] = lci[row * S_ + t];
    }
    __syncthreads();   // S0

    // ---- staging split across quarters (NT on scattered streams) ----
    if (h < 2) {
      const int r = h;
      const int row = b0 + r;
      const int lpt = s_idx[r][3], lct = s_idx[r][4];
      ushort pu = __builtin_nontemporal_load((const ushort*)psh + ((size_t)row * S_ + lpt) * 256 + d);
      ushort su = __builtin_nontemporal_load((const ushort*)ssh + ((size_t)row * S_ + lct) * 256 + d);
      sLP[r][d] = *(__half*)&pu;
      sLC[r][d] = *(__half*)&su;
      sTP[r][d] = TEpf[(t - lpt) * 256 + d];
      sTC[r][d] = TEsf[(t - lct) * 256 + d];
    } else {
      const int r = h - 2;
      int ip = s_idx[r][0], ic = s_idx[r][1], ia = s_idx[r][2];
      float ad = __builtin_nontemporal_load(adiff + ip);
      float pe = __builtin_nontemporal_load(pro + (size_t)ip * 256 + d)
               + __builtin_nontemporal_load(skill + (size_t)ic * 256 + d)
               + ad * __builtin_nontemporal_load(achg + (size_t)ic * 256 + d);
      sPE[r][d] = __float2half(pe);
      sX[r][d]  = __float2half(pe + ansv[ia * 256 + d]);
    }
    __syncthreads();   // S1

    // ---- phase 1 partials: gates (K=256), quarter h -> k-chunks [8h,8h+8) ----
    {
      const uint4* xp0 = (const uint4*)&sLP[0][0];
      const uint4* xp1 = (const uint4*)&sLP[1][0];
      const uint4* xs0 = (const uint4*)&sLC[0][0];
      const uint4* xs1 = (const uint4*)&sLC[1][0];
      const uint4* xa0 = (const uint4*)&sAS[0][0];
      const uint4* xa1 = (const uint4*)&sAS[1][0];
      const int j0 = h << 3;
      float g00 = 0.f, g01 = 0.f, g10 = 0.f, g11 = 0.f, g20 = 0.f, g21 = 0.f;
#pragma unroll
      for (int kk = 0; kk < 8; ++kk) {
        const int j = j0 + kk;
        uint4 w = Ppf[j * 256 + d];
        g00 = dot8(w, xp0[j], g00); g01 = dot8(w, xp1[j], g01);
        w = Psf[j * 256 + d];
        g10 = dot8(w, xs0[j], g10); g11 = dot8(w, xs1[j], g11);
        w = Paf[j * 256 + d];
        g20 = dot8(w, xa0[j], g20); g21 = dot8(w, xa1[j], g21);
      }
      s_part[0][tid] = g00; s_part[1][tid] = g01;
      s_part[2][tid] = g10; s_part[3][tid] = g11;
      s_part[4][tid] = g20; s_part[5][tid] = g21;
    }
    __syncthreads();   // S1b

    // ---- gate finalize (quarter 0) ----
    if (h == 0) {
#pragma unroll
      for (int r = 0; r < ROWS; ++r) {
        float g0 = s_part[0 + r][d] + s_part[0 + r][d + 256] + s_part[0 + r][d + 512] + s_part[0 + r][d + 768];
        float g1 = s_part[2 + r][d] + s_part[2 + r][d + 256] + s_part[2 + r][d + 512] + s_part[2 + r][d + 768];
        float g2 = s_part[4 + r][d] + s_part[4 + r][d + 256] + s_part[4 + r][d + 512] + s_part[4 + r][d + 768];
        float lp_v = __half2float(sLP[r][d]);
        float lc_v = __half2float(sLC[r][d]);
        float as_v = s_astf[r][d];
        float lp2 = lp_v * sigf(g0 + sTP[r][d]);
        float lc2 = lc_v * sigf(g1 + sTC[r][d]);
        float la2 = as_v * sigf(g2 + caf_d);
        s_gf[0 + r][d] = la2; s_gf[2 + r][d] = lp2; s_gf[4 + r][d] = lc2;
        sLA[r][d]  = __float2half(la2);
        sLP2[r][d] = __float2half(lp2);
        sLC2[r][d] = __float2half(lc2);
      }
    }
    __syncthreads();   // S2

    // ---- phase 2 partials: Wo1 (K=1024: la|lp2|lc2|pe) + updates (K=512: st|x) ----
    {
      const uint4* la0 = (const uint4*)&sLA[0][0];
      const uint4* la1 = (const uint4*)&sLA[1][0];
      const uint4* p20 = (const uint4*)&sLP2[0][0];
      const uint4* p21 = (const uint4*)&sLP2[1][0];
      const uint4* c20 = (const uint4*)&sLC2[0][0];
      const uint4* c21 = (const uint4*)&sLC2[1][0];
      const uint4* pe0 = (const uint4*)&sPE[0][0];
      const uint4* pe1 = (const uint4*)&sPE[1][0];
      const uint4* x0  = (const uint4*)&sX[0][0];
      const uint4* x1  = (const uint4*)&sX[1][0];
      const int j0 = h << 3;
      float aO0 = 0.f, aO1 = 0.f, aA0 = 0.f, aA1 = 0.f;
      float aP0 = 0.f, aP1 = 0.f, aC0 = 0.f, aC1 = 0.f;
#pragma unroll
      for (int kk = 0; kk < 8; ++kk) {
        const int j = j0 + kk;
        uint4 w = Po1[j * 256 + d];
        aO0 = dot8(w, la0[j], aO0); aO1 = dot8(w, la1[j], aO1);
        w = Pas[j * 256 + d];
        aA0 = dot8(w, la0[j], aA0); aA1 = dot8(w, la1[j], aA1);
        w = Pps[j * 256 + d];
        aP0 = dot8(w, p20[j], aP0); aP1 = dot8(w, p21[j], aP1);
        w = Pss[j * 256 + d];
        aC0 = dot8(w, c20[j], aC0); aC1 = dot8(w, c21[j], aC1);
      }
#pragma unroll
      for (int kk = 0; kk < 8; ++kk) {
        const int j = j0 + kk;
        uint4 w = Po1[(32 + j) * 256 + d];
        aO0 = dot8(w, p20[j], aO0); aO1 = dot8(w, p21[j], aO1);
        w = Pas[(32 + j) * 256 + d];
        aA0 = dot8(w, x0[j], aA0); aA1 = dot8(w, x1[j], aA1);
        w = Pps[(32 + j) * 256 + d];
        aP0 = dot8(w, x0[j], aP0); aP1 = dot8(w, x1[j], aP1);
        w = Pss[(32 + j) * 256 + d];
        aC0 = dot8(w, x0[j], aC0); aC1 = dot8(w, x1[j], aC1);
      }
#pragma unroll
      for (int kk = 0; kk < 8; ++kk) {
        const int j = j0 + kk;
        uint4 w = Po1[(64 + j) * 256 + d];
        aO0 = dot8(w, c20[j], aO0); aO1 = dot8(w, c21[j], aO1);
        w = Po1[(96 + j) * 256 + d];
        aO0 = dot8(w, pe0[j], aO0); aO1 = dot8(w, pe1[j], aO1);
      }
      s_part[0][tid] = aO0; s_part[1][tid] = aO1;
      s_part[2][tid] = aA0; s_part[3][tid] = aA1;
      s_part[4][tid] = aP0; s_part[5][tid] = aP1;
      s_part[6][tid] = aC0; s_part[7][tid] = aC1;
    }
    __syncthreads();   // S2b

    // ---- update finalize (quarter 0) ----
    if (h == 0) {
      const int lane = d & 63, wv = d >> 6;
#pragma unroll
      for (int r = 0; r < ROWS; ++r) {
        int row = b0 + r;
        float aO = s_part[0 + r][d] + s_part[0 + r][d + 256] + s_part[0 + r][d + 512] + s_part[0 + r][d + 768];
        float aA = s_part[2 + r][d] + s_part[2 + r][d + 256] + s_part[2 + r][d + 512] + s_part[2 + r][d + 768];
        float aP = s_part[4 + r][d] + s_part[4 + r][d + 256] + s_part[4 + r][d + 512] + s_part[4 + r][d + 768];
        float aC = s_part[6 + r][d] + s_part[6 + r][d + 256] + s_part[6 + r][d + 512] + s_part[6 + r][d + 768];
        float o1 = fmaxf(aO + bo1_d, 0.f) * wo2_d;
        o1 += __shfl_xor(o1, 32); o1 += __shfl_xor(o1, 16);
        o1 += __shfl_xor(o1, 8);  o1 += __shfl_xor(o1, 4);
        o1 += __shfl_xor(o1, 2);  o1 += __shfl_xor(o1, 1);
        if (lane == 0) s_red[wv][r] = o1;
        float la2 = s_gf[0 + r][d], lp2 = s_gf[2 + r][d], lc2 = s_gf[4 + r][d];
        float anew = la2 + tanh_fast(aA + bas_d);
        float pnew = lp2 + tanh_fast(aP + bps_d);
        float cnew = lc2 + tanh_fast(aC + bss_d);
        s_astf[r][d] = anew;
        sAS[r][d] = __float2half(anew);
        __half ph = __float2half(pnew), ch = __float2half(cnew);
        __builtin_nontemporal_store(*(ushort*)&ph,
            (ushort*)psh + ((size_t)row * S_ + t) * 256 + d);
        __builtin_nontemporal_store(*(ushort*)&ch,
            (ushort*)ssh + ((size_t)row * S_ + t) * 256 + d);
      }
    }
    __syncthreads();   // S3
    if (tid < ROWS) {
      float z = s_red[0][tid] + s_red[1][tid] + s_red[2][tid] + s_red[3][tid] + bo2v;
      out[(b0 + tid) * S_ + t] = 1.f / (1.f + __expf(-z));
    }
  }
}

extern "C" void kernel_launch(void* const* d_in, const int* in_sizes, int n_in,
                              void* d_out, int out_size, void* d_ws, size_t ws_size,
                              hipStream_t stream) {
  const int*   q_seq        = (const int*)d_in[0];
  const int*   c_seq        = (const int*)d_in[1];
  const int*   a_seq        = (const int*)d_in[2];
  const float* pro_embed    = (const float*)d_in[3];
  const float* skill_embed  = (const float*)d_in[4];
  const float* ans_embed    = (const float*)d_in[5];
  const float* time_embed   = (const float*)d_in[6];
  const float* ls_state     = (const float*)d_in[7];
  const float* pro_state0   = (const float*)d_in[8];
  const float* skill_state0 = (const float*)d_in[9];
  const float* akt_diff     = (const float*)d_in[10];
  const float* akt_change   = (const float*)d_in[11];
  const float* Wpf = (const float*)d_in[12]; const float* bpf = (const float*)d_in[13];
  const float* Wps = (const float*)d_in[14]; const float* bps = (const float*)d_in[15];
  const float* Wsf = (const float*)d_in[16]; const float* bsf = (const float*)d_in[17];
  const float* Wss = (const float*)d_in[18]; const float* bss = (const float*)d_in[19];
  const float* Waf = (const float*)d_in[20]; const float* baf = (const float*)d_in[21];
  const float* Was = (const float*)d_in[22]; const float* bas = (const float*)d_in[23];
  const float* Wo1 = (const float*)d_in[24]; const float* bo1 = (const float*)d_in[25];
  const float* Wo2 = (const float*)d_in[26]; const float* bo2 = (const float*)d_in[27];

  char* ws = (char*)d_ws;
  float* TEpf = (float*)(ws + OFF_TEPF);
  float* TEsf = (float*)(ws + OFF_TESF);
  float* CAF  = (float*)(ws + OFF_CAF);
  uint4* Ppf  = (uint4*)(ws + OFF_PPF);
  uint4* Psf  = (uint4*)(ws + OFF_PSF);
  uint4* Paf  = (uint4*)(ws + OFF_PAF);
  uint4* Pas  = (uint4*)(ws + OFF_PAS);
  uint4* Pps  = (uint4*)(ws + OFF_PPS);
  uint4* Pss  = (uint4*)(ws + OFF_PSS);
  uint4* Po1  = (uint4*)(ws + OFF_PO1);
  int*   lpi  = (int*)(ws + OFF_LPI);
  int*   lci  = (int*)(ws + OFF_LCI);
  __half* psh = (__half*)(ws + OFF_PSH);
  __half* ssh = (__half*)(ws + OFF_SSH);
  float* out  = (float*)d_out;

  te_kernel<<<200, 256, 0, stream>>>(time_embed, Wpf, bpf, Wsf, bsf, TEpf, TEsf);
  caf_kernel<<<1, 256, 0, stream>>>(time_embed, Waf, baf, CAF);
  lastidx_kernel<<<B_, 256, 0, stream>>>(q_seq, c_seq, lpi, lci);

  // gate matrices: left halves (K=256) -> 32 k8-blocks
  pack_kernel<<<32, 256, 0, stream>>>(Wpf, Ppf, 512);
  pack_kernel<<<32, 256, 0, stream>>>(Wsf, Psf, 512);
  pack_kernel<<<32, 256, 0, stream>>>(Waf, Paf, 512);
  // full K=512 update matrices
  pack_kernel<<<64, 256, 0, stream>>>(Was, Pas, 512);
  pack_kernel<<<64, 256, 0, stream>>>(Wps, Pps, 512);
  pack_kernel<<<64, 256, 0, stream>>>(Wss, Pss, 512);
  // Wo1: K=1024
  pack_kernel<<<128, 256, 0, stream>>>(Wo1, Po1, 1024);

  scan2_kernel<<<NBLK, 1024, 0, stream>>>(q_seq, c_seq, a_seq,
                                          pro_embed, skill_embed, ans_embed,
                                          ls_state, pro_state0, skill_state0,
                                          akt_diff, akt_change,
                                          TEpf, TEsf, CAF,
                                          Ppf, Psf, Paf, Pas, Pps, Pss, Po1,
                                          bo1, bas, bps, bss, Wo2, bo2,
                                          lpi, lci, psh, ssh, out);
}